// Round 8
// baseline (676.525 us; speedup 1.0000x reference)
//
#include <hip/hip_runtime.h>
#include <math.h>

// Problem constants
#define BB   16
#define SS   512
#define CC   16
#define DD   512
#define DH   64
#define FF   2048
#define LL   2
#define VV   20000
#define NTOK (BB*SS)      // 8192
#define NG   (BB*8)       // 128 attention groups
#define GRP  (SS*DH)      // 32768 elems per attention group slab
#define ST   72           // padded LDS row stride (u16) for attn tiles

typedef unsigned short u16;
typedef __attribute__((ext_vector_type(8))) short bf16x8;
typedef __attribute__((ext_vector_type(4))) float f32x4;

__device__ __forceinline__ u16 f2bf(float x) {
    unsigned u = __float_as_uint(x);
    u = (u + 0x7fffu + ((u >> 16) & 1u)) >> 16;
    return (u16)u;
}
__device__ __forceinline__ float bf2f(u16 h) {
    return __uint_as_float(((unsigned)h) << 16);
}
__device__ __forceinline__ void gload16(const void* g, void* l) {
    __builtin_amdgcn_global_load_lds((const __attribute__((address_space(1))) void*)g,
                                     (__attribute__((address_space(3))) void*)l, 16, 0, 0);
}

// ---------------------------------------------------------------------------
// Kernel 0a: fused transpose+split for Wq/Wk/Wv/Wo.  QKV rows packed into one
// [L][1536][512] B-matrix (k-contiguous); Wo into [L][512][512].
// ---------------------------------------------------------------------------
__global__ __launch_bounds__(256) void cvt_qkvo(
    const float* __restrict__ Wq, const float* __restrict__ Wk,
    const float* __restrict__ Wv, const float* __restrict__ Wo,
    u16* __restrict__ qkv_h, u16* __restrict__ qkv_l,
    u16* __restrict__ o_h,   u16* __restrict__ o_l)
{
    const int z = blockIdx.z;
    const int which = z >> 1, l = z & 1;
    const float* W = (which == 0) ? Wq : (which == 1) ? Wk : (which == 2) ? Wv : Wo;
    W += (long)l * DD * DD;
    u16 *Th, *Tl;
    if (which < 3) {
        long off = (long)l * 1536 * DD + (long)which * DD * DD;
        Th = qkv_h + off; Tl = qkv_l + off;
    } else {
        long off = (long)l * DD * DD;
        Th = o_h + off;   Tl = o_l + off;
    }
    const int n0 = blockIdx.x * 32, k0 = blockIdx.y * 32;
    __shared__ float T[32][33];
    const int t = threadIdx.x;
    {
        const int lk = t >> 3, ln4 = (t & 7) * 4;
        float4 w4 = *(const float4*)&W[(long)(k0 + lk) * DD + n0 + ln4];
        T[ln4 + 0][lk] = w4.x; T[ln4 + 1][lk] = w4.y;
        T[ln4 + 2][lk] = w4.z; T[ln4 + 3][lk] = w4.w;
    }
    __syncthreads();
    {
        const int nn = t >> 3, kq = (t & 7) * 4;
        float v0 = T[nn][kq + 0], v1 = T[nn][kq + 1];
        float v2 = T[nn][kq + 2], v3 = T[nn][kq + 3];
        ushort4 hh, ll;
        hh.x = f2bf(v0); ll.x = f2bf(v0 - bf2f(hh.x));
        hh.y = f2bf(v1); ll.y = f2bf(v1 - bf2f(hh.y));
        hh.z = f2bf(v2); ll.z = f2bf(v2 - bf2f(hh.z));
        hh.w = f2bf(v3); ll.w = f2bf(v3 - bf2f(hh.w));
        long o = (long)(n0 + nn) * DD + k0 + kq;
        *(ushort4*)&Th[o] = hh;
        *(ushort4*)&Tl[o] = ll;
    }
}

// ---------------------------------------------------------------------------
// Kernel 0b: generic transpose+split (W1, W2). grid (N/32, K/32, L)
// ---------------------------------------------------------------------------
__global__ __launch_bounds__(256) void cvt_weight(
    const float* __restrict__ W, u16* __restrict__ Th, u16* __restrict__ Tl,
    int K, int N)
{
    const long moff = (long)blockIdx.z * K * N;
    W += moff; Th += moff; Tl += moff;
    const int n0 = blockIdx.x * 32, k0 = blockIdx.y * 32;
    __shared__ float T[32][33];
    const int t = threadIdx.x;
    {
        const int lk = t >> 3, ln4 = (t & 7) * 4;
        float4 w4 = *(const float4*)&W[(long)(k0 + lk) * N + n0 + ln4];
        T[ln4 + 0][lk] = w4.x; T[ln4 + 1][lk] = w4.y;
        T[ln4 + 2][lk] = w4.z; T[ln4 + 3][lk] = w4.w;
    }
    __syncthreads();
    {
        const int nn = t >> 3, kq = (t & 7) * 4;
        float v0 = T[nn][kq + 0], v1 = T[nn][kq + 1];
        float v2 = T[nn][kq + 2], v3 = T[nn][kq + 3];
        ushort4 hh, ll;
        hh.x = f2bf(v0); ll.x = f2bf(v0 - bf2f(hh.x));
        hh.y = f2bf(v1); ll.y = f2bf(v1 - bf2f(hh.y));
        hh.z = f2bf(v2); ll.z = f2bf(v2 - bf2f(hh.z));
        hh.w = f2bf(v3); ll.w = f2bf(v3 - bf2f(hh.w));
        long o = (long)(n0 + nn) * K + k0 + kq;
        *(ushort4*)&Th[o] = hh;
        *(ushort4*)&Tl[o] = ll;
    }
}

// ---------------------------------------------------------------------------
// Kernel 0c: embedding table fp32 -> bf16
// ---------------------------------------------------------------------------
__global__ __launch_bounds__(256) void cvt_emb(const float* __restrict__ E,
                                               u16* __restrict__ E16)
{
    long i = ((long)blockIdx.x * 256 + threadIdx.x) * 4;
    float4 v = *(const float4*)&E[i];
    ushort4 o;
    o.x = f2bf(v.x); o.y = f2bf(v.y); o.z = f2bf(v.z); o.w = f2bf(v.w);
    *(ushort4*)&E16[i] = o;
}

// ---------------------------------------------------------------------------
// Kernel 1: embedding sum + time MLP + PE.  8 tokens per block (grid 1024);
// time_W read once per block (GEMM-style reuse over the 8 tokens).
// ---------------------------------------------------------------------------
__global__ __launch_bounds__(256) void embed_kernel(
    const int*   __restrict__ event_code,
    const float* __restrict__ mask_code,
    const float* __restrict__ seq_time,
    const int*   __restrict__ input_len,
    const u16*   __restrict__ emb16,
    const float* __restrict__ bias_emb,
    const float* __restrict__ sel_W,
    const float* __restrict__ sel_b,
    const float* __restrict__ time_W,
    const float* __restrict__ time_b,
    float* __restrict__ out, u16* __restrict__ oh)
{
    const int tok0 = blockIdx.x * 8;
    const int b    = tok0 >> 9;
    const int t2   = threadIdx.x;
    const int d    = t2 * 2;

    __shared__ int   codes_s[8][16];
    __shared__ float mcode_s[8][16];
    __shared__ float f_s[64][8];
    __shared__ float tvals[8];

    if (t2 < 128) {
        int tok = t2 >> 4, c = t2 & 15;
        codes_s[tok][c] = event_code[(tok0 + tok) * CC + c];
        mcode_s[tok][c] = mask_code[(tok0 + tok) * CC + c];
    }
    if (t2 < 8) tvals[t2] = seq_time[tok0 + t2] * (1.0f / 7200.0f);
    __syncthreads();

    {
        int tok = t2 >> 5;
        int j0  = (t2 & 31) * 2;
        float t = tvals[tok];
        #pragma unroll
        for (int i = 0; i < 2; ++i) {
            int j = j0 + i;
            float h = t * sel_W[j] + sel_b[j];
            f_s[j][tok] = 1.0f - tanhf(h * h);
        }
    }
    __syncthreads();

    float be0 = bias_emb[d]     + time_b[d];
    float be1 = bias_emb[d + 1] + time_b[d + 1];
    float2 acc[8];
    #pragma unroll
    for (int tok = 0; tok < 8; ++tok) { acc[tok].x = be0; acc[tok].y = be1; }

    #pragma unroll 2
    for (int c = 0; c < CC; ++c) {
        #pragma unroll
        for (int tok = 0; tok < 8; ++tok) {
            unsigned pk = *(const unsigned*)&emb16[(long)codes_s[tok][c] * DD + d];
            float mc = mcode_s[tok][c];
            acc[tok].x += bf2f((u16)(pk & 0xffffu)) * mc;
            acc[tok].y += bf2f((u16)(pk >> 16))     * mc;
        }
    }

    #pragma unroll 4
    for (int j = 0; j < 64; ++j) {
        float2 tw = *(const float2*)&time_W[j * DD + d];
        float4 f0 = *(const float4*)&f_s[j][0];
        float4 f1 = *(const float4*)&f_s[j][4];
        float fv[8] = {f0.x, f0.y, f0.z, f0.w, f1.x, f1.y, f1.z, f1.w};
        #pragma unroll
        for (int tok = 0; tok < 8; ++tok) {
            acc[tok].x += fv[tok] * tw.x;
            acc[tok].y += fv[tok] * tw.y;
        }
    }

    float e    = (float)d * (1.0f / 512.0f);
    float invf = exp2f(-13.287712379549449f * e);   // 10000^-e
    int ilen = input_len[b];
    #pragma unroll
    for (int tok = 0; tok < 8; ++tok) {
        int s = (tok0 + tok) & 511;
        if (s + 1 <= ilen) {
            float ang = (float)s * invf;
            acc[tok].x += sinf(ang);
            acc[tok].y += cosf(ang);
        }
    }

    #pragma unroll
    for (int tok = 0; tok < 8; ++tok) {
        long o = (long)(tok0 + tok) * DD + d;
        *(float2*)&out[o] = acc[tok];
        unsigned pk = (unsigned)f2bf(acc[tok].x) | ((unsigned)f2bf(acc[tok].y) << 16);
        *(unsigned*)&oh[o] = pk;
    }
}

// ---------------------------------------------------------------------------
// Kernel 2: MFMA GEMM, 2-phase double-buffered pipeline.
// Chunk-major LDS layout (pre-swizzled global source, linear LDS dest):
// [16-row group][k-chunk (l>>4)][row (l&15)] x 16B  -> frag ds_read_b128 hits
// 2 lanes/bank (free) instead of 8-way conflict of row-major stride-64B.
// EMIT: 0 = fp32, 2 = bf16. SEG3: split output cols into 3 [*,512] buffers.
// ---------------------------------------------------------------------------
template<int BN, bool RELU, bool RES, int EMIT, bool SEG3>
__global__ __launch_bounds__(256) void mgemm(
    const u16* __restrict__ A,
    const u16* __restrict__ Bh, const u16* __restrict__ Bl,
    const float* __restrict__ bias0, const float* __restrict__ bias1,
    const float* __restrict__ bias2,
    const float* __restrict__ res,
    float* __restrict__ C,
    u16* __restrict__ O0, u16* __restrict__ O1, u16* __restrict__ O2,
    int N, int K)
{
    constexpr int WN  = BN / 2;
    constexpr int NI  = WN / 16;
    constexpr int LPW = 2 + 2 * (BN / 64);   // gload_lds per wave per tile
    __shared__ __align__(16) u16 A_s[2][128 * 32];
    __shared__ __align__(16) u16 Bh_s[2][BN * 32];
    __shared__ __align__(16) u16 Bl_s[2][BN * 32];

    const int tid  = threadIdx.x;
    const int wid  = tid >> 6, lane = tid & 63;
    const int wr   = wid >> 1, wc = wid & 1;
    const int l4   = lane >> 4, l15 = lane & 15;

    // XCD swizzle (nwg % 8 == 0 in all our grids)
    const int bid  = blockIdx.x + gridDim.x * blockIdx.y;
    const int xcd  = bid & 7;
    const int slot = bid >> 3;
    const int ppx  = gridDim.y >> 3;
    const int by   = xcd * ppx + slot / gridDim.x;
    const int bx   = slot % gridDim.x;
    const int m0   = by * 128, n0 = bx * BN;
    // chunk-major staging map: lane -> (row = lane&15, k-chunk = lane>>4)
    const int sr   = lane & 15, sc = lane >> 4;

    auto STAGE = [&](int bufi, int k0) {
        #pragma unroll
        for (int i = 0; i < 2; ++i) {
            int rr = wid * 32 + i * 16;
            long go = (long)(m0 + rr + sr) * K + k0 + sc * 8;
            gload16(A + go, &A_s[bufi][rr * 32]);
        }
        #pragma unroll
        for (int i = 0; i < BN / 64; ++i) {
            int rr = wid * (BN / 4) + i * 16;
            long go = (long)(n0 + rr + sr) * K + k0 + sc * 8;
            gload16(Bh + go, &Bh_s[bufi][rr * 32]);
            gload16(Bl + go, &Bl_s[bufi][rr * 32]);
        }
    };

    f32x4 acc[4][NI];
    #pragma unroll
    for (int mi = 0; mi < 4; ++mi)
        #pragma unroll
        for (int ni = 0; ni < NI; ++ni)
            acc[mi][ni] = (f32x4){0.f, 0.f, 0.f, 0.f};

    STAGE(0, 0);
    const int nt = K / 32;
    for (int t = 0; t < nt; ++t) {
        const int cur = t & 1;
        if (t + 1 < nt) {
            STAGE(cur ^ 1, (t + 1) * 32);
            asm volatile("s_waitcnt vmcnt(%0)" :: "i"(LPW) : "memory");
        } else {
            asm volatile("s_waitcnt vmcnt(0)" ::: "memory");
        }
        __builtin_amdgcn_s_barrier();   // current tile fully resident

        // frag reads from chunk-major layout: group*512 + l4*128 + l15*8 (u16)
        bf16x8 af[4], bh[NI], bl[NI];
        #pragma unroll
        for (int mi = 0; mi < 4; ++mi) {
            int grp = wr * 4 + mi;
            af[mi] = *(const bf16x8*)&A_s[cur][grp * 512 + l4 * 128 + l15 * 8];
        }
        #pragma unroll
        for (int ni = 0; ni < NI; ++ni) {
            int grp = wc * NI + ni;
            bh[ni] = *(const bf16x8*)&Bh_s[cur][grp * 512 + l4 * 128 + l15 * 8];
            bl[ni] = *(const bf16x8*)&Bl_s[cur][grp * 512 + l4 * 128 + l15 * 8];
        }
        asm volatile("s_waitcnt lgkmcnt(0)" ::: "memory");
        __builtin_amdgcn_sched_barrier(0);
        __builtin_amdgcn_s_barrier();   // all reads done -> buffer reusable

        #pragma unroll
        for (int mi = 0; mi < 4; ++mi)
            #pragma unroll
            for (int ni = 0; ni < NI; ++ni) {
                acc[mi][ni] = __builtin_amdgcn_mfma_f32_16x16x32_bf16(af[mi], bh[ni], acc[mi][ni], 0, 0, 0);
                acc[mi][ni] = __builtin_amdgcn_mfma_f32_16x16x32_bf16(af[mi], bl[ni], acc[mi][ni], 0, 0, 0);
            }
    }

    // epilogue: C/D frag mapping col = lane&15, row = (lane>>4)*4 + reg
    #pragma unroll
    for (int mi = 0; mi < 4; ++mi)
        #pragma unroll
        for (int ni = 0; ni < NI; ++ni) {
            int colg = n0 + wc * WN + ni * 16 + l15;
            int seg  = SEG3 ? (colg >> 9) : 0;
            int coll = SEG3 ? (colg & 511) : colg;
            const float* bp = SEG3 ? (seg == 0 ? bias0 : seg == 1 ? bias1 : bias2) : bias0;
            u16* op = SEG3 ? (seg == 0 ? O0 : seg == 1 ? O1 : O2) : O0;
            const int ost = SEG3 ? 512 : N;
            float bv = bp[coll];
            #pragma unroll
            for (int r = 0; r < 4; ++r) {
                int row = m0 + wr * 64 + mi * 16 + l4 * 4 + r;
                long off = (long)row * ost + coll;
                float v = acc[mi][ni][r] + bv;
                if (RES) v += res[off];
                if (RELU) v = fmaxf(v, 0.f);
                if (EMIT == 2) op[off] = f2bf(v);
                else           C[off]  = v;
            }
        }
}

// ---------------------------------------------------------------------------
// Kernel 3: MFMA flash-attention over 128 contiguous [512x64] slabs.
// XCD-swizzled so a group's 8 query-tile blocks share one XCD's L2.
// ---------------------------------------------------------------------------
__global__ __launch_bounds__(256) void attn_kernel(
    const u16* __restrict__ Qg, const u16* __restrict__ Kg, const u16* __restrict__ Vg,
    u16* __restrict__ Oh)
{
    const int bid = blockIdx.x;
    const int xcd = bid & 7, slot = bid >> 3;      // 1024 blocks
    const int g   = xcd * 16 + (slot >> 3);        // 16 groups per XCD
    const int qt  = slot & 7;
    const int tid = threadIdx.x;
    const int w   = tid >> 6;
    const int lane = tid & 63;
    const int l4  = lane >> 4, l15 = lane & 15;

    __shared__ __align__(16) u16 Qs[64 * ST];
    __shared__ __align__(16) u16 Ks[64 * ST];
    __shared__ __align__(16) u16 Vt[64 * ST];   // V^T: [d][k]
    __shared__ __align__(16) u16 Ps[64 * ST];   // P:   [q][k]

    const long gbase = (long)g * GRP;

    {
        const u16* src = Qg + gbase + (long)qt * 64 * 64;
        #pragma unroll
        for (int i = 0; i < 2; ++i) {
            int slot2 = tid + i * 256;
            int row = slot2 >> 3, c8 = slot2 & 7;
            *(int4*)&Qs[row * ST + c8 * 8] = *(const int4*)&src[row * 64 + c8 * 8];
        }
    }
    __syncthreads();

    const bf16x8 qf0 = *(const bf16x8*)&Qs[(w * 16 + l15) * ST + l4 * 8];
    const bf16x8 qf1 = *(const bf16x8*)&Qs[(w * 16 + l15) * ST + 32 + l4 * 8];

    f32x4 oacc[4];
    #pragma unroll
    for (int db = 0; db < 4; ++db) oacc[db] = (f32x4){0.f, 0.f, 0.f, 0.f};
    float mrun = -3e38f, lrun = 0.f;

    const int k0t = (tid >> 4) * 4;
    const int d0t = (tid & 15) * 4;

    for (int kt = 0; kt < 8; ++kt) {
        const u16* ksrc = Kg + gbase + (long)kt * 4096;
        const u16* vsrc = Vg + gbase + (long)kt * 4096;
        #pragma unroll
        for (int i = 0; i < 2; ++i) {
            int slot2 = tid + i * 256;
            int row = slot2 >> 3, c8 = slot2 & 7;
            *(int4*)&Ks[row * ST + c8 * 8] = *(const int4*)&ksrc[row * 64 + c8 * 8];
        }
        {   // V 4x4 register transpose -> Vt[d][k]
            ushort4 r0 = *(const ushort4*)&vsrc[(k0t + 0) * 64 + d0t];
            ushort4 r1 = *(const ushort4*)&vsrc[(k0t + 1) * 64 + d0t];
            ushort4 r2 = *(const ushort4*)&vsrc[(k0t + 2) * 64 + d0t];
            ushort4 r3 = *(const ushort4*)&vsrc[(k0t + 3) * 64 + d0t];
            ushort4 t0, t1, t2, t3;
            t0.x = r0.x; t0.y = r1.x; t0.z = r2.x; t0.w = r3.x;
            t1.x = r0.y; t1.y = r1.y; t1.z = r2.y; t1.w = r3.y;
            t2.x = r0.z; t2.y = r1.z; t2.z = r2.z; t2.w = r3.z;
            t3.x = r0.w; t3.y = r1.w; t3.z = r2.w; t3.w = r3.w;
            *(ushort4*)&Vt[(d0t + 0) * ST + k0t] = t0;
            *(ushort4*)&Vt[(d0t + 1) * ST + k0t] = t1;
            *(ushort4*)&Vt[(d0t + 2) * ST + k0t] = t2;
            *(ushort4*)&Vt[(d0t + 3) * ST + k0t] = t3;
        }
        __syncthreads();

        f32x4 sacc[4];
        #pragma unroll
        for (int kb = 0; kb < 4; ++kb) {
            bf16x8 a0 = *(const bf16x8*)&Ks[(kb * 16 + l15) * ST + l4 * 8];
            bf16x8 a1 = *(const bf16x8*)&Ks[(kb * 16 + l15) * ST + 32 + l4 * 8];
            f32x4 z = (f32x4){0.f, 0.f, 0.f, 0.f};
            z = __builtin_amdgcn_mfma_f32_16x16x32_bf16(a0, qf0, z, 0, 0, 0);
            z = __builtin_amdgcn_mfma_f32_16x16x32_bf16(a1, qf1, z, 0, 0, 0);
            sacc[kb] = z;
        }

        float pm = -3e38f;
        #pragma unroll
        for (int kb = 0; kb < 4; ++kb)
            #pragma unroll
            for (int r = 0; r < 4; ++r)
                pm = fmaxf(pm, sacc[kb][r]);
        pm *= 0.125f;
        pm = fmaxf(pm, __shfl_xor(pm, 16));
        pm = fmaxf(pm, __shfl_xor(pm, 32));
        float mn   = fmaxf(mrun, pm);
        float corr = __expf(mrun - mn);
        float psum = 0.f;
        u16 pb[16];
        #pragma unroll
        for (int kb = 0; kb < 4; ++kb)
            #pragma unroll
            for (int r = 0; r < 4; ++r) {
                float p = __expf(sacc[kb][r] * 0.125f - mn);
                u16 b = f2bf(p);
                pb[kb * 4 + r] = b;
                psum += bf2f(b);
            }
        psum += __shfl_xor(psum, 16);
        psum += __shfl_xor(psum, 32);
        lrun = lrun * corr + psum;
        mrun = mn;

        #pragma unroll
        for (int kb = 0; kb < 4; ++kb)
            #pragma unroll
            for (int r = 0; r < 4; ++r)
                Ps[(w * 16 + l15) * ST + kb * 16 + l4 * 4 + r] = pb[kb * 4 + r];

        float cr[4];
        #pragma unroll
        for (int r = 0; r < 4; ++r) cr[r] = __shfl(corr, l4 * 4 + r);
        #pragma unroll
        for (int db = 0; db < 4; ++db)
            #pragma unroll
            for (int r = 0; r < 4; ++r)
                oacc[db][r] *= cr[r];

        asm volatile("s_waitcnt lgkmcnt(0)" ::: "memory");
        __builtin_amdgcn_sched_barrier(0);
        bf16x8 pa0 = *(const bf16x8*)&Ps[(w * 16 + l15) * ST + l4 * 8];
        bf16x8 pa1 = *(const bf16x8*)&Ps[(w * 16 + l15) * ST + 32 + l4 * 8];
        #pragma unroll
        for (int db = 0; db < 4; ++db) {
            bf16x8 v0 = *(const bf16x8*)&Vt[(db * 16 + l15) * ST + l4 * 8];
            bf16x8 v1 = *(const bf16x8*)&Vt[(db * 16 + l15) * ST + 32 + l4 * 8];
            oacc[db] = __builtin_amdgcn_mfma_f32_16x16x32_bf16(pa0, v0, oacc[db], 0, 0, 0);
            oacc[db] = __builtin_amdgcn_mfma_f32_16x16x32_bf16(pa1, v1, oacc[db], 0, 0, 0);
        }
        __syncthreads();
    }

    float li[4];
    #pragma unroll
    for (int r = 0; r < 4; ++r) li[r] = 1.0f / __shfl(lrun, l4 * 4 + r);
    #pragma unroll
    for (int db = 0; db < 4; ++db)
        #pragma unroll
        for (int r = 0; r < 4; ++r) {
            float val = oacc[db][r] * li[r];
            long addr = gbase + (long)(qt * 64 + w * 16 + l4 * 4 + r) * 64 + db * 16 + l15;
            Oh[addr] = f2bf(val);
        }
}

// ---------------------------------------------------------------------------
// Kernel 4: LayerNorm over D=512; emits fp32 + bf16
// ---------------------------------------------------------------------------
__global__ __launch_bounds__(256) void ln_kernel(
    const float* __restrict__ X,
    const float* __restrict__ gam,
    const float* __restrict__ bet,
    float* __restrict__ Y, u16* __restrict__ Yh,
    float eps)
{
    const int row = blockIdx.x;
    const int tid = threadIdx.x;
    const float* x = X + (long)row * DD;

    float x0 = x[tid], x1 = x[tid + 256];
    __shared__ float ws4[4];
    const int wid = tid >> 6, lane = tid & 63;

    float sum = x0 + x1;
    #pragma unroll
    for (int off = 32; off > 0; off >>= 1) sum += __shfl_down(sum, off, 64);
    if (lane == 0) ws4[wid] = sum;
    __syncthreads();
    float mean = (ws4[0] + ws4[1] + ws4[2] + ws4[3]) * (1.0f / 512.0f);
    __syncthreads();

    float d0 = x0 - mean, d1 = x1 - mean;
    float s2 = d0 * d0 + d1 * d1;
    #pragma unroll
    for (int off = 32; off > 0; off >>= 1) s2 += __shfl_down(s2, off, 64);
    if (lane == 0) ws4[wid] = s2;
    __syncthreads();
    float var = (ws4[0] + ws4[1] + ws4[2] + ws4[3]) * (1.0f / 512.0f);
    float inv = rsqrtf(var + eps);

    float o0 = d0 * inv * gam[tid]       + bet[tid];
    float o1 = d1 * inv * gam[tid + 256] + bet[tid + 256];
    long b0 = (long)row * DD + tid;
    Y[b0] = o0;  Y[b0 + 256] = o1;
    Yh[b0] = f2bf(o0);
    Yh[b0 + 256] = f2bf(o1);
}

// ---------------------------------------------------------------------------
extern "C" void kernel_launch(void* const* d_in, const int* in_sizes, int n_in,
                              void* d_out, int out_size, void* d_ws, size_t ws_size,
                              hipStream_t stream)
{
    const int*   event_code = (const int*)  d_in[0];
    const float* mask_code  = (const float*)d_in[2];
    const float* seq_time   = (const float*)d_in[3];
    const int*   input_len  = (const int*)  d_in[6];
    const float* emb        = (const float*)d_in[7];
    const float* bias_emb   = (const float*)d_in[8];
    const float* sel_W      = (const float*)d_in[9];
    const float* sel_b      = (const float*)d_in[10];
    const float* time_W     = (const float*)d_in[11];
    const float* time_b     = (const float*)d_in[12];
    const float* Wq  = (const float*)d_in[13];
    const float* bq  = (const float*)d_in[14];
    const float* Wk  = (const float*)d_in[15];
    const float* bk  = (const float*)d_in[16];
    const float* Wv  = (const float*)d_in[17];
    const float* bv  = (const float*)d_in[18];
    const float* Wo  = (const float*)d_in[19];
    const float* bo  = (const float*)d_in[20];
    const float* ln1g = (const float*)d_in[21];
    const float* ln1b = (const float*)d_in[22];
    const float* W1  = (const float*)d_in[23];
    const float* b1  = (const float*)d_in[24];
    const float* W2  = (const float*)d_in[25];
    const float* b2  = (const float*)d_in[26];
    const float* ln2g = (const float*)d_in[27];
    const float* ln2b = (const float*)d_in[28];

    float* ws = (float*)d_ws;
    const long ND = (long)NTOK * DD;      // 4.19M elems
    const long NF = (long)NTOK * FF;
    float* x = ws;                        // fp32 residual
    float* y = ws + ND;
    u16* q16 = (u16*)(ws + 2 * ND);       // bf16 QKV
    u16* k16 = q16 + ND;
    u16* v16 = k16 + ND;
    u16* a16 = v16 + ND;                  // bf16 activations
    u16* h16 = a16 + ND;                  // FFN hidden bf16
    u16* e16 = h16 + NF;                  // bf16 embedding table [V,512]
    u16* wqkv_h = e16 + (long)VV * DD;    // packed QKV weights [L][1536][512]
    const long SZ3 = (long)LL * 1536 * DD;
    const long SZQ = (long)LL * DD * DD, SZF = (long)LL * DD * FF;
    u16* wqkv_l = wqkv_h + SZ3;
    u16* wo_h = wqkv_l + SZ3;  u16* wo_l = wo_h + SZQ;
    u16* w1_h = wo_l + SZQ;    u16* w1_l = w1_h + SZF;
    u16* w2_h = w1_l + SZF;    u16* w2_l = w2_h + SZF;

    cvt_qkvo<<<dim3(16, 16, 8), 256, 0, stream>>>(Wq, Wk, Wv, Wo, wqkv_h, wqkv_l, wo_h, wo_l);
    cvt_weight<<<dim3(FF/32, DD/32, LL), 256, 0, stream>>>(W1, w1_h, w1_l, DD, FF);
    cvt_weight<<<dim3(DD/32, FF/32, LL), 256, 0, stream>>>(W2, w2_h, w2_l, FF, DD);
    cvt_emb<<<(VV * DD) / 1024, 256, 0, stream>>>(emb, e16);

    embed_kernel<<<NTOK / 8, 256, 0, stream>>>(event_code, mask_code, seq_time, input_len,
                                               e16, bias_emb, sel_W, sel_b, time_W, time_b,
                                               x, a16);

    const dim3 gQKV(1536 / 64, NTOK / 128);  // (24,64) = 1536 blocks
    const dim3 gN512(DD / 64, NTOK / 128);   // (8,64)  = 512 blocks
    const dim3 gN2048(FF / 128, NTOK / 128); // (16,64) = 1024 blocks

    for (int l = 0; l < LL; ++l) {
        const u16* qkvh = wqkv_h + (long)l * 1536 * DD;
        const u16* qkvl = wqkv_l + (long)l * 1536 * DD;
        const u16* oh = wo_h + (long)l * DD * DD;  const u16* ol = wo_l + (long)l * DD * DD;
        const u16* f1h = w1_h + (long)l * DD * FF; const u16* f1l = w1_l + (long)l * DD * FF;
        const u16* f2h = w2_h + (long)l * FF * DD; const u16* f2l = w2_l + (long)l * FF * DD;

        // merged QKV projection -> bf16 q16/k16/v16
        mgemm<64,false,false,2,true><<<gQKV, 256, 0, stream>>>(
            a16, qkvh, qkvl, bq + l*DD, bk + l*DD, bv + l*DD, nullptr,
            nullptr, q16, k16, v16, 1536, DD);

        // ctx (bf16) into a16
        attn_kernel<<<NG * 8, 256, 0, stream>>>(q16, k16, v16, a16);

        // y = x + ctx@Wo + bo ; LN1 (eps 1e-3)
        mgemm<64,false,true,0,false><<<gN512, 256, 0, stream>>>(
            a16, oh, ol, bo + l*DD, nullptr, nullptr, x,
            y, nullptr, nullptr, nullptr, DD, DD);
        ln_kernel<<<NTOK, 256, 0, stream>>>(y, ln1g + l*DD, ln1b + l*DD, y, a16, 1e-3f);

        // h = relu(y@W1 + b1) -> bf16
        mgemm<128,true,false,2,false><<<gN2048, 256, 0, stream>>>(
            a16, f1h, f1l, b1 + l*FF, nullptr, nullptr, nullptr,
            nullptr, h16, nullptr, nullptr, FF, DD);
        // x = y + h@W2 + b2 ; LN2 (eps 1e-6)
        mgemm<64,false,true,0,false><<<gN512, 256, 0, stream>>>(
            h16, f2h, f2l, b2 + l*DD, nullptr, nullptr, y,
            x, nullptr, nullptr, nullptr, DD, FF);

        float* lnout = (l == LL - 1) ? (float*)d_out : x;
        ln_kernel<<<NTOK, 256, 0, stream>>>(x, ln2g + l*DD, ln2b + l*DD, lnout, a16, 1e-6f);
    }
}

// Round 9
// 554.973 us; speedup vs baseline: 1.2190x; 1.2190x over previous
//
#include <hip/hip_runtime.h>
#include <math.h>

// Problem constants
#define BB   16
#define SS   512
#define CC   16
#define DD   512
#define DH   64
#define FF   2048
#define LL   2
#define VV   20000
#define NTOK (BB*SS)      // 8192
#define NG   (BB*8)       // 128 attention groups
#define GRP  (SS*DH)      // 32768 elems per attention group slab
#define ST   72           // padded LDS row stride (u16) for attn tiles

typedef unsigned short u16;
typedef __attribute__((ext_vector_type(8))) short bf16x8;
typedef __attribute__((ext_vector_type(4))) float f32x4;

__device__ __forceinline__ u16 f2bf(float x) {
    unsigned u = __float_as_uint(x);
    u = (u + 0x7fffu + ((u >> 16) & 1u)) >> 16;
    return (u16)u;
}
__device__ __forceinline__ float bf2f(u16 h) {
    return __uint_as_float(((unsigned)h) << 16);
}
__device__ __forceinline__ void gload16(const void* g, void* l) {
    __builtin_amdgcn_global_load_lds((const __attribute__((address_space(1))) void*)g,
                                     (__attribute__((address_space(3))) void*)l, 16, 0, 0);
}

// ---------------------------------------------------------------------------
// Kernel 0a: fused transpose+split for Wq/Wk/Wv/Wo.  QKV rows packed into one
// [L][1536][512] B-matrix (k-contiguous); Wo into [L][512][512].
// ---------------------------------------------------------------------------
__global__ __launch_bounds__(256) void cvt_qkvo(
    const float* __restrict__ Wq, const float* __restrict__ Wk,
    const float* __restrict__ Wv, const float* __restrict__ Wo,
    u16* __restrict__ qkv_h, u16* __restrict__ qkv_l,
    u16* __restrict__ o_h,   u16* __restrict__ o_l)
{
    const int z = blockIdx.z;
    const int which = z >> 1, l = z & 1;
    const float* W = (which == 0) ? Wq : (which == 1) ? Wk : (which == 2) ? Wv : Wo;
    W += (long)l * DD * DD;
    u16 *Th, *Tl;
    if (which < 3) {
        long off = (long)l * 1536 * DD + (long)which * DD * DD;
        Th = qkv_h + off; Tl = qkv_l + off;
    } else {
        long off = (long)l * DD * DD;
        Th = o_h + off;   Tl = o_l + off;
    }
    const int n0 = blockIdx.x * 32, k0 = blockIdx.y * 32;
    __shared__ float T[32][33];
    const int t = threadIdx.x;
    {
        const int lk = t >> 3, ln4 = (t & 7) * 4;
        float4 w4 = *(const float4*)&W[(long)(k0 + lk) * DD + n0 + ln4];
        T[ln4 + 0][lk] = w4.x; T[ln4 + 1][lk] = w4.y;
        T[ln4 + 2][lk] = w4.z; T[ln4 + 3][lk] = w4.w;
    }
    __syncthreads();
    {
        const int nn = t >> 3, kq = (t & 7) * 4;
        float v0 = T[nn][kq + 0], v1 = T[nn][kq + 1];
        float v2 = T[nn][kq + 2], v3 = T[nn][kq + 3];
        ushort4 hh, ll;
        hh.x = f2bf(v0); ll.x = f2bf(v0 - bf2f(hh.x));
        hh.y = f2bf(v1); ll.y = f2bf(v1 - bf2f(hh.y));
        hh.z = f2bf(v2); ll.z = f2bf(v2 - bf2f(hh.z));
        hh.w = f2bf(v3); ll.w = f2bf(v3 - bf2f(hh.w));
        long o = (long)(n0 + nn) * DD + k0 + kq;
        *(ushort4*)&Th[o] = hh;
        *(ushort4*)&Tl[o] = ll;
    }
}

// ---------------------------------------------------------------------------
// Kernel 0b: generic transpose+split (W1, W2). grid (N/32, K/32, L)
// ---------------------------------------------------------------------------
__global__ __launch_bounds__(256) void cvt_weight(
    const float* __restrict__ W, u16* __restrict__ Th, u16* __restrict__ Tl,
    int K, int N)
{
    const long moff = (long)blockIdx.z * K * N;
    W += moff; Th += moff; Tl += moff;
    const int n0 = blockIdx.x * 32, k0 = blockIdx.y * 32;
    __shared__ float T[32][33];
    const int t = threadIdx.x;
    {
        const int lk = t >> 3, ln4 = (t & 7) * 4;
        float4 w4 = *(const float4*)&W[(long)(k0 + lk) * N + n0 + ln4];
        T[ln4 + 0][lk] = w4.x; T[ln4 + 1][lk] = w4.y;
        T[ln4 + 2][lk] = w4.z; T[ln4 + 3][lk] = w4.w;
    }
    __syncthreads();
    {
        const int nn = t >> 3, kq = (t & 7) * 4;
        float v0 = T[nn][kq + 0], v1 = T[nn][kq + 1];
        float v2 = T[nn][kq + 2], v3 = T[nn][kq + 3];
        ushort4 hh, ll;
        hh.x = f2bf(v0); ll.x = f2bf(v0 - bf2f(hh.x));
        hh.y = f2bf(v1); ll.y = f2bf(v1 - bf2f(hh.y));
        hh.z = f2bf(v2); ll.z = f2bf(v2 - bf2f(hh.z));
        hh.w = f2bf(v3); ll.w = f2bf(v3 - bf2f(hh.w));
        long o = (long)(n0 + nn) * K + k0 + kq;
        *(ushort4*)&Th[o] = hh;
        *(ushort4*)&Tl[o] = ll;
    }
}

// ---------------------------------------------------------------------------
// Kernel 0c: embedding table fp32 -> bf16
// ---------------------------------------------------------------------------
__global__ __launch_bounds__(256) void cvt_emb(const float* __restrict__ E,
                                               u16* __restrict__ E16)
{
    long i = ((long)blockIdx.x * 256 + threadIdx.x) * 4;
    float4 v = *(const float4*)&E[i];
    ushort4 o;
    o.x = f2bf(v.x); o.y = f2bf(v.y); o.z = f2bf(v.z); o.w = f2bf(v.w);
    *(ushort4*)&E16[i] = o;
}

// ---------------------------------------------------------------------------
// Kernel 1: embedding sum + time MLP + PE.  8 tokens per block (grid 1024);
// time_W read once per block (GEMM-style reuse over the 8 tokens).
// ---------------------------------------------------------------------------
__global__ __launch_bounds__(256) void embed_kernel(
    const int*   __restrict__ event_code,
    const float* __restrict__ mask_code,
    const float* __restrict__ seq_time,
    const int*   __restrict__ input_len,
    const u16*   __restrict__ emb16,
    const float* __restrict__ bias_emb,
    const float* __restrict__ sel_W,
    const float* __restrict__ sel_b,
    const float* __restrict__ time_W,
    const float* __restrict__ time_b,
    float* __restrict__ out, u16* __restrict__ oh)
{
    const int tok0 = blockIdx.x * 8;
    const int b    = tok0 >> 9;
    const int t2   = threadIdx.x;
    const int d    = t2 * 2;

    __shared__ int   codes_s[8][16];
    __shared__ float mcode_s[8][16];
    __shared__ float f_s[64][8];
    __shared__ float tvals[8];

    if (t2 < 128) {
        int tok = t2 >> 4, c = t2 & 15;
        codes_s[tok][c] = event_code[(tok0 + tok) * CC + c];
        mcode_s[tok][c] = mask_code[(tok0 + tok) * CC + c];
    }
    if (t2 < 8) tvals[t2] = seq_time[tok0 + t2] * (1.0f / 7200.0f);
    __syncthreads();

    {
        int tok = t2 >> 5;
        int j0  = (t2 & 31) * 2;
        float t = tvals[tok];
        #pragma unroll
        for (int i = 0; i < 2; ++i) {
            int j = j0 + i;
            float h = t * sel_W[j] + sel_b[j];
            f_s[j][tok] = 1.0f - tanhf(h * h);
        }
    }
    __syncthreads();

    float be0 = bias_emb[d]     + time_b[d];
    float be1 = bias_emb[d + 1] + time_b[d + 1];
    float2 acc[8];
    #pragma unroll
    for (int tok = 0; tok < 8; ++tok) { acc[tok].x = be0; acc[tok].y = be1; }

    #pragma unroll 2
    for (int c = 0; c < CC; ++c) {
        #pragma unroll
        for (int tok = 0; tok < 8; ++tok) {
            unsigned pk = *(const unsigned*)&emb16[(long)codes_s[tok][c] * DD + d];
            float mc = mcode_s[tok][c];
            acc[tok].x += bf2f((u16)(pk & 0xffffu)) * mc;
            acc[tok].y += bf2f((u16)(pk >> 16))     * mc;
        }
    }

    #pragma unroll 4
    for (int j = 0; j < 64; ++j) {
        float2 tw = *(const float2*)&time_W[j * DD + d];
        float4 f0 = *(const float4*)&f_s[j][0];
        float4 f1 = *(const float4*)&f_s[j][4];
        float fv[8] = {f0.x, f0.y, f0.z, f0.w, f1.x, f1.y, f1.z, f1.w};
        #pragma unroll
        for (int tok = 0; tok < 8; ++tok) {
            acc[tok].x += fv[tok] * tw.x;
            acc[tok].y += fv[tok] * tw.y;
        }
    }

    float e    = (float)d * (1.0f / 512.0f);
    float invf = exp2f(-13.287712379549449f * e);   // 10000^-e
    int ilen = input_len[b];
    #pragma unroll
    for (int tok = 0; tok < 8; ++tok) {
        int s = (tok0 + tok) & 511;
        if (s + 1 <= ilen) {
            float ang = (float)s * invf;
            acc[tok].x += sinf(ang);
            acc[tok].y += cosf(ang);
        }
    }

    #pragma unroll
    for (int tok = 0; tok < 8; ++tok) {
        long o = (long)(tok0 + tok) * DD + d;
        *(float2*)&out[o] = acc[tok];
        unsigned pk = (unsigned)f2bf(acc[tok].x) | ((unsigned)f2bf(acc[tok].y) << 16);
        *(unsigned*)&oh[o] = pk;
    }
}

// ---------------------------------------------------------------------------
// Kernel 2: MFMA GEMM, 2-phase double-buffered pipeline.
// Staging keeps R7's coalesced quad map (lanes 0-3 = one row's 64B) but
// rotates the k-chunk within each quad by (row>>1): slot(r,c) = r*4 +
// (c + (r>>1))%4. Frag ds_read_b128 then hits all 8 bank-quads with 2
// lanes each (2-way = free) instead of 8-way; global coalescing unchanged.
// EMIT: 0 = fp32, 2 = bf16. SEG3: split output cols into 3 [*,512] buffers.
// ---------------------------------------------------------------------------
template<int BN, bool RELU, bool RES, int EMIT, bool SEG3>
__global__ __launch_bounds__(256) void mgemm(
    const u16* __restrict__ A,
    const u16* __restrict__ Bh, const u16* __restrict__ Bl,
    const float* __restrict__ bias0, const float* __restrict__ bias1,
    const float* __restrict__ bias2,
    const float* __restrict__ res,
    float* __restrict__ C,
    u16* __restrict__ O0, u16* __restrict__ O1, u16* __restrict__ O2,
    int N, int K)
{
    constexpr int WN  = BN / 2;
    constexpr int NI  = WN / 16;
    constexpr int LPW = 2 + 2 * (BN / 64);   // gload_lds per wave per tile
    __shared__ __align__(16) u16 A_s[2][128 * 32];
    __shared__ __align__(16) u16 Bh_s[2][BN * 32];
    __shared__ __align__(16) u16 Bl_s[2][BN * 32];

    const int tid  = threadIdx.x;
    const int wid  = tid >> 6, lane = tid & 63;
    const int wr   = wid >> 1, wc = wid & 1;
    const int l4   = lane >> 4, l15 = lane & 15;

    // XCD swizzle (nwg % 8 == 0 in all our grids)
    const int bid  = blockIdx.x + gridDim.x * blockIdx.y;
    const int xcd  = bid & 7;
    const int slot = bid >> 3;
    const int ppx  = gridDim.y >> 3;
    const int by   = xcd * ppx + slot / gridDim.x;
    const int bx   = slot % gridDim.x;
    const int m0   = by * 128, n0 = bx * BN;
    // staging map: row = lane>>2 (quads contiguous in global), chunk rotated
    // within the quad so LDS slot r*4+(c+(r>>1))%4 deconflicts frag reads
    const int sr   = lane >> 2;
    const int sc   = ((lane & 3) - (lane >> 3)) & 3;

    auto STAGE = [&](int bufi, int k0) {
        #pragma unroll
        for (int i = 0; i < 2; ++i) {
            int rr = wid * 32 + i * 16;
            long go = (long)(m0 + rr + sr) * K + k0 + sc * 8;
            gload16(A + go, &A_s[bufi][rr * 32]);
        }
        #pragma unroll
        for (int i = 0; i < BN / 64; ++i) {
            int rr = wid * (BN / 4) + i * 16;
            long go = (long)(n0 + rr + sr) * K + k0 + sc * 8;
            gload16(Bh + go, &Bh_s[bufi][rr * 32]);
            gload16(Bl + go, &Bl_s[bufi][rr * 32]);
        }
    };

    f32x4 acc[4][NI];
    #pragma unroll
    for (int mi = 0; mi < 4; ++mi)
        #pragma unroll
        for (int ni = 0; ni < NI; ++ni)
            acc[mi][ni] = (f32x4){0.f, 0.f, 0.f, 0.f};

    STAGE(0, 0);
    const int nt = K / 32;
    // frag read offset within a 16-row group (u16): row l15, chunk l4
    const int frag_off = l15 * 32 + (((l4 + (l15 >> 1)) & 3) * 8);
    for (int t = 0; t < nt; ++t) {
        const int cur = t & 1;
        if (t + 1 < nt) {
            STAGE(cur ^ 1, (t + 1) * 32);
            asm volatile("s_waitcnt vmcnt(%0)" :: "i"(LPW) : "memory");
        } else {
            asm volatile("s_waitcnt vmcnt(0)" ::: "memory");
        }
        __builtin_amdgcn_s_barrier();   // current tile fully resident

        bf16x8 af[4], bh[NI], bl[NI];
        #pragma unroll
        for (int mi = 0; mi < 4; ++mi) {
            int grp = wr * 4 + mi;
            af[mi] = *(const bf16x8*)&A_s[cur][grp * 512 + frag_off];
        }
        #pragma unroll
        for (int ni = 0; ni < NI; ++ni) {
            int grp = wc * NI + ni;
            bh[ni] = *(const bf16x8*)&Bh_s[cur][grp * 512 + frag_off];
            bl[ni] = *(const bf16x8*)&Bl_s[cur][grp * 512 + frag_off];
        }
        asm volatile("s_waitcnt lgkmcnt(0)" ::: "memory");
        __builtin_amdgcn_sched_barrier(0);
        __builtin_amdgcn_s_barrier();   // all reads done -> buffer reusable

        #pragma unroll
        for (int mi = 0; mi < 4; ++mi)
            #pragma unroll
            for (int ni = 0; ni < NI; ++ni) {
                acc[mi][ni] = __builtin_amdgcn_mfma_f32_16x16x32_bf16(af[mi], bh[ni], acc[mi][ni], 0, 0, 0);
                acc[mi][ni] = __builtin_amdgcn_mfma_f32_16x16x32_bf16(af[mi], bl[ni], acc[mi][ni], 0, 0, 0);
            }
    }

    // epilogue: C/D frag mapping col = lane&15, row = (lane>>4)*4 + reg
    #pragma unroll
    for (int mi = 0; mi < 4; ++mi)
        #pragma unroll
        for (int ni = 0; ni < NI; ++ni) {
            int colg = n0 + wc * WN + ni * 16 + l15;
            int seg  = SEG3 ? (colg >> 9) : 0;
            int coll = SEG3 ? (colg & 511) : colg;
            const float* bp = SEG3 ? (seg == 0 ? bias0 : seg == 1 ? bias1 : bias2) : bias0;
            u16* op = SEG3 ? (seg == 0 ? O0 : seg == 1 ? O1 : O2) : O0;
            const int ost = SEG3 ? 512 : N;
            float bv = bp[coll];
            #pragma unroll
            for (int r = 0; r < 4; ++r) {
                int row = m0 + wr * 64 + mi * 16 + l4 * 4 + r;
                long off = (long)row * ost + coll;
                float v = acc[mi][ni][r] + bv;
                if (RES) v += res[off];
                if (RELU) v = fmaxf(v, 0.f);
                if (EMIT == 2) op[off] = f2bf(v);
                else           C[off]  = v;
            }
        }
}

// ---------------------------------------------------------------------------
// Kernel 3: MFMA flash-attention over 128 contiguous [512x64] slabs.
// XCD-swizzled so a group's 8 query-tile blocks share one XCD's L2.
// ---------------------------------------------------------------------------
__global__ __launch_bounds__(256) void attn_kernel(
    const u16* __restrict__ Qg, const u16* __restrict__ Kg, const u16* __restrict__ Vg,
    u16* __restrict__ Oh)
{
    const int bid = blockIdx.x;
    const int xcd = bid & 7, slot = bid >> 3;      // 1024 blocks
    const int g   = xcd * 16 + (slot >> 3);        // 16 groups per XCD
    const int qt  = slot & 7;
    const int tid = threadIdx.x;
    const int w   = tid >> 6;
    const int lane = tid & 63;
    const int l4  = lane >> 4, l15 = lane & 15;

    __shared__ __align__(16) u16 Qs[64 * ST];
    __shared__ __align__(16) u16 Ks[64 * ST];
    __shared__ __align__(16) u16 Vt[64 * ST];   // V^T: [d][k]
    __shared__ __align__(16) u16 Ps[64 * ST];   // P:   [q][k]

    const long gbase = (long)g * GRP;

    {
        const u16* src = Qg + gbase + (long)qt * 64 * 64;
        #pragma unroll
        for (int i = 0; i < 2; ++i) {
            int slot2 = tid + i * 256;
            int row = slot2 >> 3, c8 = slot2 & 7;
            *(int4*)&Qs[row * ST + c8 * 8] = *(const int4*)&src[row * 64 + c8 * 8];
        }
    }
    __syncthreads();

    const bf16x8 qf0 = *(const bf16x8*)&Qs[(w * 16 + l15) * ST + l4 * 8];
    const bf16x8 qf1 = *(const bf16x8*)&Qs[(w * 16 + l15) * ST + 32 + l4 * 8];

    f32x4 oacc[4];
    #pragma unroll
    for (int db = 0; db < 4; ++db) oacc[db] = (f32x4){0.f, 0.f, 0.f, 0.f};
    float mrun = -3e38f, lrun = 0.f;

    const int k0t = (tid >> 4) * 4;
    const int d0t = (tid & 15) * 4;

    for (int kt = 0; kt < 8; ++kt) {
        const u16* ksrc = Kg + gbase + (long)kt * 4096;
        const u16* vsrc = Vg + gbase + (long)kt * 4096;
        #pragma unroll
        for (int i = 0; i < 2; ++i) {
            int slot2 = tid + i * 256;
            int row = slot2 >> 3, c8 = slot2 & 7;
            *(int4*)&Ks[row * ST + c8 * 8] = *(const int4*)&ksrc[row * 64 + c8 * 8];
        }
        {   // V 4x4 register transpose -> Vt[d][k]
            ushort4 r0 = *(const ushort4*)&vsrc[(k0t + 0) * 64 + d0t];
            ushort4 r1 = *(const ushort4*)&vsrc[(k0t + 1) * 64 + d0t];
            ushort4 r2 = *(const ushort4*)&vsrc[(k0t + 2) * 64 + d0t];
            ushort4 r3 = *(const ushort4*)&vsrc[(k0t + 3) * 64 + d0t];
            ushort4 t0, t1, t2, t3;
            t0.x = r0.x; t0.y = r1.x; t0.z = r2.x; t0.w = r3.x;
            t1.x = r0.y; t1.y = r1.y; t1.z = r2.y; t1.w = r3.y;
            t2.x = r0.z; t2.y = r1.z; t2.z = r2.z; t2.w = r3.z;
            t3.x = r0.w; t3.y = r1.w; t3.z = r2.w; t3.w = r3.w;
            *(ushort4*)&Vt[(d0t + 0) * ST + k0t] = t0;
            *(ushort4*)&Vt[(d0t + 1) * ST + k0t] = t1;
            *(ushort4*)&Vt[(d0t + 2) * ST + k0t] = t2;
            *(ushort4*)&Vt[(d0t + 3) * ST + k0t] = t3;
        }
        __syncthreads();

        f32x4 sacc[4];
        #pragma unroll
        for (int kb = 0; kb < 4; ++kb) {
            bf16x8 a0 = *(const bf16x8*)&Ks[(kb * 16 + l15) * ST + l4 * 8];
            bf16x8 a1 = *(const bf16x8*)&Ks[(kb * 16 + l15) * ST + 32 + l4 * 8];
            f32x4 z = (f32x4){0.f, 0.f, 0.f, 0.f};
            z = __builtin_amdgcn_mfma_f32_16x16x32_bf16(a0, qf0, z, 0, 0, 0);
            z = __builtin_amdgcn_mfma_f32_16x16x32_bf16(a1, qf1, z, 0, 0, 0);
            sacc[kb] = z;
        }

        float pm = -3e38f;
        #pragma unroll
        for (int kb = 0; kb < 4; ++kb)
            #pragma unroll
            for (int r = 0; r < 4; ++r)
                pm = fmaxf(pm, sacc[kb][r]);
        pm *= 0.125f;
        pm = fmaxf(pm, __shfl_xor(pm, 16));
        pm = fmaxf(pm, __shfl_xor(pm, 32));
        float mn   = fmaxf(mrun, pm);
        float corr = __expf(mrun - mn);
        float psum = 0.f;
        u16 pb[16];
        #pragma unroll
        for (int kb = 0; kb < 4; ++kb)
            #pragma unroll
            for (int r = 0; r < 4; ++r) {
                float p = __expf(sacc[kb][r] * 0.125f - mn);
                u16 b = f2bf(p);
                pb[kb * 4 + r] = b;
                psum += bf2f(b);
            }
        psum += __shfl_xor(psum, 16);
        psum += __shfl_xor(psum, 32);
        lrun = lrun * corr + psum;
        mrun = mn;

        #pragma unroll
        for (int kb = 0; kb < 4; ++kb)
            #pragma unroll
            for (int r = 0; r < 4; ++r)
                Ps[(w * 16 + l15) * ST + kb * 16 + l4 * 4 + r] = pb[kb * 4 + r];

        float cr[4];
        #pragma unroll
        for (int r = 0; r < 4; ++r) cr[r] = __shfl(corr, l4 * 4 + r);
        #pragma unroll
        for (int db = 0; db < 4; ++db)
            #pragma unroll
            for (int r = 0; r < 4; ++r)
                oacc[db][r] *= cr[r];

        asm volatile("s_waitcnt lgkmcnt(0)" ::: "memory");
        __builtin_amdgcn_sched_barrier(0);
        bf16x8 pa0 = *(const bf16x8*)&Ps[(w * 16 + l15) * ST + l4 * 8];
        bf16x8 pa1 = *(const bf16x8*)&Ps[(w * 16 + l15) * ST + 32 + l4 * 8];
        #pragma unroll
        for (int db = 0; db < 4; ++db) {
            bf16x8 v0 = *(const bf16x8*)&Vt[(db * 16 + l15) * ST + l4 * 8];
            bf16x8 v1 = *(const bf16x8*)&Vt[(db * 16 + l15) * ST + 32 + l4 * 8];
            oacc[db] = __builtin_amdgcn_mfma_f32_16x16x32_bf16(pa0, v0, oacc[db], 0, 0, 0);
            oacc[db] = __builtin_amdgcn_mfma_f32_16x16x32_bf16(pa1, v1, oacc[db], 0, 0, 0);
        }
        __syncthreads();
    }

    float li[4];
    #pragma unroll
    for (int r = 0; r < 4; ++r) li[r] = 1.0f / __shfl(lrun, l4 * 4 + r);
    #pragma unroll
    for (int db = 0; db < 4; ++db)
        #pragma unroll
        for (int r = 0; r < 4; ++r) {
            float val = oacc[db][r] * li[r];
            long addr = gbase + (long)(qt * 64 + w * 16 + l4 * 4 + r) * 64 + db * 16 + l15;
            Oh[addr] = f2bf(val);
        }
}

// ---------------------------------------------------------------------------
// Kernel 4: LayerNorm over D=512; emits fp32 + bf16
// ---------------------------------------------------------------------------
__global__ __launch_bounds__(256) void ln_kernel(
    const float* __restrict__ X,
    const float* __restrict__ gam,
    const float* __restrict__ bet,
    float* __restrict__ Y, u16* __restrict__ Yh,
    float eps)
{
    const int row = blockIdx.x;
    const int tid = threadIdx.x;
    const float* x = X + (long)row * DD;

    float x0 = x[tid], x1 = x[tid + 256];
    __shared__ float ws4[4];
    const int wid = tid >> 6, lane = tid & 63;

    float sum = x0 + x1;
    #pragma unroll
    for (int off = 32; off > 0; off >>= 1) sum += __shfl_down(sum, off, 64);
    if (lane == 0) ws4[wid] = sum;
    __syncthreads();
    float mean = (ws4[0] + ws4[1] + ws4[2] + ws4[3]) * (1.0f / 512.0f);
    __syncthreads();

    float d0 = x0 - mean, d1 = x1 - mean;
    float s2 = d0 * d0 + d1 * d1;
    #pragma unroll
    for (int off = 32; off > 0; off >>= 1) s2 += __shfl_down(s2, off, 64);
    if (lane == 0) ws4[wid] = s2;
    __syncthreads();
    float var = (ws4[0] + ws4[1] + ws4[2] + ws4[3]) * (1.0f / 512.0f);
    float inv = rsqrtf(var + eps);

    float o0 = d0 * inv * gam[tid]       + bet[tid];
    float o1 = d1 * inv * gam[tid + 256] + bet[tid + 256];
    long b0 = (long)row * DD + tid;
    Y[b0] = o0;  Y[b0 + 256] = o1;
    Yh[b0] = f2bf(o0);
    Yh[b0 + 256] = f2bf(o1);
}

// ---------------------------------------------------------------------------
extern "C" void kernel_launch(void* const* d_in, const int* in_sizes, int n_in,
                              void* d_out, int out_size, void* d_ws, size_t ws_size,
                              hipStream_t stream)
{
    const int*   event_code = (const int*)  d_in[0];
    const float* mask_code  = (const float*)d_in[2];
    const float* seq_time   = (const float*)d_in[3];
    const int*   input_len  = (const int*)  d_in[6];
    const float* emb        = (const float*)d_in[7];
    const float* bias_emb   = (const float*)d_in[8];
    const float* sel_W      = (const float*)d_in[9];
    const float* sel_b      = (const float*)d_in[10];
    const float* time_W     = (const float*)d_in[11];
    const float* time_b     = (const float*)d_in[12];
    const float* Wq  = (const float*)d_in[13];
    const float* bq  = (const float*)d_in[14];
    const float* Wk  = (const float*)d_in[15];
    const float* bk  = (const float*)d_in[16];
    const float* Wv  = (const float*)d_in[17];
    const float* bv  = (const float*)d_in[18];
    const float* Wo  = (const float*)d_in[19];
    const float* bo  = (const float*)d_in[20];
    const float* ln1g = (const float*)d_in[21];
    const float* ln1b = (const float*)d_in[22];
    const float* W1  = (const float*)d_in[23];
    const float* b1  = (const float*)d_in[24];
    const float* W2  = (const float*)d_in[25];
    const float* b2  = (const float*)d_in[26];
    const float* ln2g = (const float*)d_in[27];
    const float* ln2b = (const float*)d_in[28];

    float* ws = (float*)d_ws;
    const long ND = (long)NTOK * DD;      // 4.19M elems
    const long NF = (long)NTOK * FF;
    float* x = ws;                        // fp32 residual
    float* y = ws + ND;
    u16* q16 = (u16*)(ws + 2 * ND);       // bf16 QKV
    u16* k16 = q16 + ND;
    u16* v16 = k16 + ND;
    u16* a16 = v16 + ND;                  // bf16 activations
    u16* h16 = a16 + ND;                  // FFN hidden bf16
    u16* e16 = h16 + NF;                  // bf16 embedding table [V,512]
    u16* wqkv_h = e16 + (long)VV * DD;    // packed QKV weights [L][1536][512]
    const long SZ3 = (long)LL * 1536 * DD;
    const long SZQ = (long)LL * DD * DD, SZF = (long)LL * DD * FF;
    u16* wqkv_l = wqkv_h + SZ3;
    u16* wo_h = wqkv_l + SZ3;  u16* wo_l = wo_h + SZQ;
    u16* w1_h = wo_l + SZQ;    u16* w1_l = w1_h + SZF;
    u16* w2_h = w1_l + SZF;    u16* w2_l = w2_h + SZF;

    cvt_qkvo<<<dim3(16, 16, 8), 256, 0, stream>>>(Wq, Wk, Wv, Wo, wqkv_h, wqkv_l, wo_h, wo_l);
    cvt_weight<<<dim3(FF/32, DD/32, LL), 256, 0, stream>>>(W1, w1_h, w1_l, DD, FF);
    cvt_weight<<<dim3(DD/32, FF/32, LL), 256, 0, stream>>>(W2, w2_h, w2_l, FF, DD);
    cvt_emb<<<(VV * DD) / 1024, 256, 0, stream>>>(emb, e16);

    embed_kernel<<<NTOK / 8, 256, 0, stream>>>(event_code, mask_code, seq_time, input_len,
                                               e16, bias_emb, sel_W, sel_b, time_W, time_b,
                                               x, a16);

    const dim3 gQKV(1536 / 64, NTOK / 128);  // (24,64) = 1536 blocks
    const dim3 gN512(DD / 64, NTOK / 128);   // (8,64)  = 512 blocks
    const dim3 gN2048(FF / 128, NTOK / 128); // (16,64) = 1024 blocks

    for (int l = 0; l < LL; ++l) {
        const u16* qkvh = wqkv_h + (long)l * 1536 * DD;
        const u16* qkvl = wqkv_l + (long)l * 1536 * DD;
        const u16* oh = wo_h + (long)l * DD * DD;  const u16* ol = wo_l + (long)l * DD * DD;
        const u16* f1h = w1_h + (long)l * DD * FF; const u16* f1l = w1_l + (long)l * DD * FF;
        const u16* f2h = w2_h + (long)l * FF * DD; const u16* f2l = w2_l + (long)l * FF * DD;

        // merged QKV projection -> bf16 q16/k16/v16
        mgemm<64,false,false,2,true><<<gQKV, 256, 0, stream>>>(
            a16, qkvh, qkvl, bq + l*DD, bk + l*DD, bv + l*DD, nullptr,
            nullptr, q16, k16, v16, 1536, DD);

        // ctx (bf16) into a16
        attn_kernel<<<NG * 8, 256, 0, stream>>>(q16, k16, v16, a16);

        // y = x + ctx@Wo + bo ; LN1 (eps 1e-3)
        mgemm<64,false,true,0,false><<<gN512, 256, 0, stream>>>(
            a16, oh, ol, bo + l*DD, nullptr, nullptr, x,
            y, nullptr, nullptr, nullptr, DD, DD);
        ln_kernel<<<NTOK, 256, 0, stream>>>(y, ln1g + l*DD, ln1b + l*DD, y, a16, 1e-3f);

        // h = relu(y@W1 + b1) -> bf16
        mgemm<128,true,false,2,false><<<gN2048, 256, 0, stream>>>(
            a16, f1h, f1l, b1 + l*FF, nullptr, nullptr, nullptr,
            nullptr, h16, nullptr, nullptr, FF, DD);
        // x = y + h@W2 + b2 ; LN2 (eps 1e-6)
        mgemm<64,false,true,0,false><<<gN512, 256, 0, stream>>>(
            h16, f2h, f2l, b2 + l*DD, nullptr, nullptr, y,
            x, nullptr, nullptr, nullptr, DD, FF);

        float* lnout = (l == LL - 1) ? (float*)d_out : x;
        ln_kernel<<<NTOK, 256, 0, stream>>>(x, ln2g + l*DD, ln2b + l*DD, lnout, a16, 1e-6f);
    }
}